// Round 11
// baseline (3885.331 us; speedup 1.0000x reference)
//
#include <hip/hip_runtime.h>

#define NN     100000
#define NP     100096   // padded: = 391 * 256
#define HD     128
#define NE     400000
#define TOT    2400000  // 6 * NE
#define L6P    (NP * 6)
#define NLAYER 8
#define SCHUNK 2048
#define CHROWS 50176    // layer chunk (agg 77MB; WS ~148MB < 256MB L3)
#define NREG   391      // 256-node target regions
#define RCAP   8192     // region bucket capacity (avg 6138)
#define BSEG   9375     // edges per k_bin1 block (256 blocks)

typedef unsigned short ushort_t;
typedef unsigned int   uint_t;

typedef __bf16 bf16x8 __attribute__((ext_vector_type(8)));
typedef float  f32x4  __attribute__((ext_vector_type(4)));

__device__ __forceinline__ f32x4 mfma16(bf16x8 a, bf16x8 b, f32x4 c) {
  return __builtin_amdgcn_mfma_f32_16x16x32_bf16(a, b, c, 0, 0, 0);
}

__device__ __forceinline__ unsigned short f2bf(float f) {
  unsigned int u = __builtin_bit_cast(unsigned int, f);
  u = (u + 0x7FFFu + ((u >> 16) & 1u)) >> 16;
  return (unsigned short)u;
}
__device__ __forceinline__ float bflo(uint_t v) { return __builtin_bit_cast(float, v << 16); }
__device__ __forceinline__ float bfhi(uint_t v) { return __builtin_bit_cast(float, v & 0xFFFF0000u); }
__device__ __forceinline__ float bf2f(ushort_t v) { return __builtin_bit_cast(float, (uint_t)v << 16); }
__device__ __forceinline__ uint_t packbf(float x, float y) {
  return (uint_t)f2bf(x) | ((uint_t)f2bf(y) << 16);
}

#define GLOAD_LDS16(g, l) __builtin_amdgcn_global_load_lds( \
    (__attribute__((address_space(1))) void*)(g),           \
    (__attribute__((address_space(3))) void*)(l), 16, 0, 0)

// ---------- setup kernels (once per call) ----------

__global__ __launch_bounds__(256) void k_init(const float* __restrict__ ns,
    float* __restrict__ oh, float* __restrict__ oold, ushort_t* __restrict__ hbf) {
  int i = blockIdx.x * 256 + threadIdx.x;
  if (i < NN * HD) {
    float v = ns[i];
    oh[i] = v; oold[i] = v; hbf[i] = f2bf(v);
  }
}

__global__ __launch_bounds__(256) void k_prep(const float* __restrict__ Wm,
    const float* __restrict__ wih, const float* __restrict__ whh,
    ushort_t* __restrict__ Wcat, ushort_t* __restrict__ wihb, ushort_t* __restrict__ whhb) {
  int t = blockIdx.x * 256 + threadIdx.x;
  if (t < 128 * 768) {
    int n = t / 768, k = t % 768;
    int e = k >> 7, d = k & 127;
    Wcat[t] = f2bf(Wm[(e * 128 + d) * 128 + n]);   // [n][k], N-major
  }
  if (t < 384 * 128) {
    wihb[t] = f2bf(wih[t]);
    whhb[t] = f2bf(whh[t]);
  }
}

// Pass A: block-local counting sort by target region, contiguous writeout.
// One global atomicAdd per (block,region) -- no contention (r6 lesson).
__global__ __launch_bounds__(256) void k_bin1(const int* __restrict__ edges,
    int* __restrict__ rcnt, int* __restrict__ rbuf) {
  __shared__ int hist[392], lbase[392], cur[392], gb[392], scanb[256];
  __shared__ int lsort[BSEG];
  int t = threadIdx.x;
  int e0 = blockIdx.x * BSEG;
  int e1 = e0 + BSEG < TOT ? e0 + BSEG : TOT;
  int cnt = e1 - e0;
  for (int i = t; i < 392; i += 256) hist[i] = 0;
  __syncthreads();
  for (int i = e0 + t; i < e1; i += 256) {
    int e = i / NE, m = i - e * NE;
    int tgt = (e < 3) ? edges[(e * NE + m) * 2 + 1] : edges[((e - 3) * NE + m) * 2];
    atomicAdd(&hist[tgt >> 8], 1);
  }
  __syncthreads();
  // scan: thread t owns hist[2t], hist[2t+1] (t<196)
  int h0 = hist[2 * t], h1 = (2 * t + 1 < 392) ? hist[2 * t + 1] : 0;
  scanb[t] = h0 + h1;
  __syncthreads();
  for (int off = 1; off < 256; off <<= 1) {
    int x = (t >= off) ? scanb[t - off] : 0;
    __syncthreads();
    scanb[t] += x;
    __syncthreads();
  }
  int excl = scanb[t] - (h0 + h1);
  if (2 * t < 392)     lbase[2 * t] = excl;
  if (2 * t + 1 < 392) lbase[2 * t + 1] = excl + h0;
  __syncthreads();
  for (int r = t; r < NREG; r += 256) {
    int h = hist[r];
    gb[r] = h ? atomicAdd(&rcnt[r], h) : 0;
    cur[r] = lbase[r];
  }
  __syncthreads();
  for (int i = e0 + t; i < e1; i += 256) {
    int e = i / NE, m = i - e * NE;
    int src, tgt;
    if (e < 3) { int b = (e * NE + m) * 2;       src = edges[b];     tgt = edges[b + 1]; }
    else       { int b = ((e - 3) * NE + m) * 2; src = edges[b + 1]; tgt = edges[b]; }
    int lp = atomicAdd(&cur[tgt >> 8], 1);
    lsort[lp] = src | (e << 17) | ((tgt & 255) << 20);
  }
  __syncthreads();
  for (int i = t; i < cnt; i += 256) {
    int lo = 0, hi = NREG - 1;                 // find r: lbase[r] <= i
    while (lo < hi) { int mid = (lo + hi + 1) >> 1; if (lbase[mid] <= i) lo = mid; else hi = mid - 1; }
    rbuf[(size_t)lo * RCAP + gb[lo] + (i - lbase[lo])] = lsort[i];
  }
}

// Pass B: per-region LDS histogram -> dense cnt6
__global__ __launch_bounds__(256) void k_bin2(const int* __restrict__ rcnt,
    const int* __restrict__ rbuf, int* __restrict__ cnt6) {
  __shared__ int hist[1536];
  int R = blockIdx.x;
#pragma unroll
  for (int j = 0; j < 6; j++) hist[threadIdx.x + j * 256] = 0;
  __syncthreads();
  int n = rcnt[R];
  for (int i = threadIdx.x; i < n; i += 256) {
    int v = rbuf[(size_t)R * RCAP + i];
    atomicAdd(&hist[((v >> 20) & 255) * 6 + ((v >> 17) & 7)], 1);
  }
  __syncthreads();
#pragma unroll
  for (int j = 0; j < 6; j++) {
    int idx = threadIdx.x + j * 256;
    cnt6[(size_t)R * 1536 + idx] = hist[idx];
  }
}

// Pass C: per-region CSR fill; LDS cursors, entries window L2-resident
__global__ __launch_bounds__(256) void k_bin3(const int* __restrict__ rcnt,
    const int* __restrict__ rbuf, const int* __restrict__ offs6,
    int* __restrict__ entries) {
  __shared__ int curloc[1536];
  int R = blockIdx.x;
#pragma unroll
  for (int j = 0; j < 6; j++) {
    int idx = threadIdx.x + j * 256;
    curloc[idx] = offs6[(size_t)R * 1536 + idx];
  }
  __syncthreads();
  int n = rcnt[R];
  for (int i = threadIdx.x; i < n; i += 256) {
    int v = rbuf[(size_t)R * RCAP + i];
    int idx = ((v >> 20) & 255) * 6 + ((v >> 17) & 7);
    int pos = atomicAdd(&curloc[idx], 1);
    entries[pos] = v & 0x1FFFF;
  }
}

__global__ __launch_bounds__(256) void k_div(const int* __restrict__ cnt6,
    float* __restrict__ divf) {
  int i = blockIdx.x * 256 + threadIdx.x;
  if (i < NP) {
    int c = 0;
#pragma unroll
    for (int e = 0; e < 6; e++) c += cnt6[i * 6 + e];
    divf[i] = c ? (float)c : 1.0f;
  }
}

// exclusive scan over cnt6 (length L6P) -> offs6
__global__ __launch_bounds__(256) void k_scan1(const int* __restrict__ cnt, int* __restrict__ bsum) {
  int base = blockIdx.x * SCHUNK + threadIdx.x * 8;
  int s = 0;
#pragma unroll
  for (int j = 0; j < 8; j++) { int idx = base + j; s += (idx < L6P) ? cnt[idx] : 0; }
  for (int o = 32; o > 0; o >>= 1) s += __shfl_down(s, o);
  __shared__ int sm[4];
  if ((threadIdx.x & 63) == 0) sm[threadIdx.x >> 6] = s;
  __syncthreads();
  if (threadIdx.x == 0) bsum[blockIdx.x] = sm[0] + sm[1] + sm[2] + sm[3];
}

__global__ __launch_bounds__(512) void k_scan2(int* __restrict__ bsum, int nb) { // 1 block, nb<=512
  int t = threadIdx.x, lane = t & 63, wv = t >> 6;
  int orig = (t < nb) ? bsum[t] : 0;
  int v = orig;
  for (int o = 1; o < 64; o <<= 1) { int x = __shfl_up(v, o); if (lane >= o) v += x; }
  __shared__ int ws[8];
  if (lane == 63) ws[wv] = v;
  __syncthreads();
  int add = 0;
  for (int w = 0; w < wv; w++) add += ws[w];
  if (t < nb) bsum[t] = v - orig + add;   // exclusive
}

__global__ __launch_bounds__(256) void k_scan3(const int* __restrict__ cnt,
    const int* __restrict__ bsum, int* __restrict__ offs) {
  int base = blockIdx.x * SCHUNK + threadIdx.x * 8;
  int vals[8], pre[8];
  int s = 0;
#pragma unroll
  for (int j = 0; j < 8; j++) {
    int idx = base + j;
    vals[j] = (idx < L6P) ? cnt[idx] : 0;
    pre[j] = s; s += vals[j];
  }
  int lane = threadIdx.x & 63, wvi = threadIdx.x >> 6;
  int v = s;
  for (int o = 1; o < 64; o <<= 1) { int t = __shfl_up(v, o); if (lane >= o) v += t; }
  __shared__ int wsum[4];
  if (lane == 63) wsum[wvi] = v;
  __syncthreads();
  int wpre = 0;
  for (int w = 0; w < wvi; w++) wpre += wsum[w];
  int texcl = (v - s) + wpre + bsum[blockIdx.x];
#pragma unroll
  for (int j = 0; j < 8; j++) {
    int idx = base + j;
    if (idx < L6P) {
      offs[idx] = texcl + pre[j];
      if (idx == L6P - 1) offs[L6P] = texcl + pre[j] + vals[j];
    }
  }
}

// ---------- per-layer kernels ----------

// Dual-node wave aggregation: each wave runs TWO independent node pipelines
// interleaved (issue0, issue1, acc0, acc1) -> 2x independent load chains.
// All state constant-indexed (structs + switch/unroll) to stay in registers.
struct AggS {
  float a[12];     // per-type (x,y), switch-indexed only
  float cx, cy;
  uint_t v[8];     // in-flight gather values (unroll-indexed)
  int bj, ent;     // per-lane regs read via readlane
  int S0, total, nextB, curE;
  int j, curC, gcnt;
};

__device__ __forceinline__ void aggFlush(AggS& s) {
  switch (s.curE) {
    case 0: s.a[0] += s.cx; s.a[1] += s.cy; break;
    case 1: s.a[2] += s.cx; s.a[3] += s.cy; break;
    case 2: s.a[4] += s.cx; s.a[5] += s.cy; break;
    case 3: s.a[6] += s.cx; s.a[7] += s.cy; break;
    case 4: s.a[8] += s.cx; s.a[9] += s.cy; break;
    default: s.a[10] += s.cx; s.a[11] += s.cy; break;
  }
  s.cx = 0.f; s.cy = 0.f;
}

__device__ __forceinline__ void aggInit(AggS& s, int n, int lane, int voff,
    const int* __restrict__ offs6, const int* __restrict__ entries,
    const char* __restrict__ hb, bool live) {
#pragma unroll
  for (int u = 0; u < 12; u++) s.a[u] = 0.f;
  s.cx = 0.f; s.cy = 0.f; s.curE = 0;
  s.j = 0; s.curC = 0; s.gcnt = 0; s.total = 0;
  if (!live) return;
  s.bj = offs6[n * 6 + (lane < 6 ? lane : 6)];
  s.S0    = __builtin_amdgcn_readlane(s.bj, 0);
  s.total = __builtin_amdgcn_readlane(s.bj, 6) - s.S0;
  s.nextB = __builtin_amdgcn_readlane(s.bj, 1) - s.S0;
  if (s.total > 0) {
    s.ent = entries[s.S0 + (lane < s.total ? lane : s.total - 1)];
    int lim = s.total < 64 ? s.total : 64;
    s.gcnt = lim < 8 ? lim : 8;
#pragma unroll
    for (int u = 0; u < 8; u++)
      if (u < s.gcnt) {
        int si = __builtin_amdgcn_readlane(s.ent, u);
        s.v[u] = *(const uint_t*)(hb + ((size_t)(uint_t)si << 8) + voff);
      }
  }
}

__device__ __forceinline__ void aggStep(AggS& s, int lane, int voff,
    const int* __restrict__ entries, const char* __restrict__ hb) {
  if (s.gcnt <= 0) return;
  int jn = s.j + s.gcnt;
  uint_t w[8];
  int ncnt = 0;
  if (jn < s.total) {
    if (jn >= s.curC + 64) {
      s.curC += 64;
      int rem = s.total - s.curC;
      s.ent = entries[s.S0 + s.curC + (lane < rem ? lane : rem - 1)];
    }
    int lim = s.total < s.curC + 64 ? s.total : s.curC + 64;
    ncnt = lim - jn; if (ncnt > 8) ncnt = 8;
#pragma unroll
    for (int u = 0; u < 8; u++)
      if (u < ncnt) {
        int si = __builtin_amdgcn_readlane(s.ent, jn + u - s.curC);
        w[u] = *(const uint_t*)(hb + ((size_t)(uint_t)si << 8) + voff);
      }
  }
#pragma unroll
  for (int u = 0; u < 8; u++) {
    if (u < s.gcnt) {
      while (s.curE < 5 && s.j + u == s.nextB) {
        aggFlush(s); s.curE++;
        s.nextB = __builtin_amdgcn_readlane(s.bj, s.curE + 1) - s.S0;
      }
      s.cx += bflo(s.v[u]); s.cy += bfhi(s.v[u]);
    }
  }
  s.j = jn; s.gcnt = ncnt;
#pragma unroll
  for (int u = 0; u < 8; u++) s.v[u] = w[u];
}

__device__ __forceinline__ void aggFinish(AggS& s) {
  while (s.curE < 5) { aggFlush(s); s.curE++; }
  aggFlush(s);
}

__global__ __launch_bounds__(512) void k_agg(const ushort_t* __restrict__ hbf,
    const int* __restrict__ offs6, const int* __restrict__ entries,
    ushort_t* __restrict__ agg, int node0, int rows) {
  int lane = threadIdx.x & 63, wv = threadIdx.x >> 6;
  int wid = blockIdx.x * 8 + wv;
  int r0 = wid * 2, r1 = wid * 2 + 1;
  if (r0 >= rows) return;
  bool live1 = (r1 < rows);
  int voff = lane * 4;
  const char* hb = (const char*)hbf;
  AggS s0, s1;
  aggInit(s0, node0 + r0, lane, voff, offs6, entries, hb, true);
  aggInit(s1, node0 + r1, lane, voff, offs6, entries, hb, live1);
  while (s0.gcnt > 0 || s1.gcnt > 0) {
    aggStep(s0, lane, voff, entries, hb);
    aggStep(s1, lane, voff, entries, hb);
  }
  aggFinish(s0);
  aggFinish(s1);
  {
    uint_t* outp = (uint_t*)(agg + (size_t)r0 * 768);
#pragma unroll
    for (int e2 = 0; e2 < 6; e2++) outp[e2 * 64 + lane] = packbf(s0.a[2 * e2], s0.a[2 * e2 + 1]);
  }
  if (live1) {
    uint_t* outp = (uint_t*)(agg + (size_t)r1 * 768);
#pragma unroll
    for (int e2 = 0; e2 < 6; e2++) outp[e2 * 64 + lane] = packbf(s1.a[2 * e2], s1.a[2 * e2 + 1]);
  }
}

// Fused msgs-GEMM + GRU. Block = 128 nodes, 8 waves, 64KB LDS.
__global__ __launch_bounds__(512, 2) void k_fused(
    const ushort_t* __restrict__ agg, const ushort_t* __restrict__ Wcat,
    const int* __restrict__ cnt6, const float* __restrict__ divf,
    const float* __restrict__ b_msg, const ushort_t* __restrict__ hbfin,
    const ushort_t* __restrict__ wihb, const ushort_t* __restrict__ whhb,
    const float* __restrict__ b_ih, const float* __restrict__ b_hh,
    float* __restrict__ hf, ushort_t* __restrict__ hbfout,
    int node0, int last) {
  __shared__ char smem[65536];
  char* Alds = smem;             // 16KB (phase A), 128 rows x 128B
  char* Blds = smem + 16384;     // 16KB (phase A)
  char* Mlds = smem + 32768;     // 32KB msgs tile, 128 rows x 256B
  char* Hlds = smem;             // 32KB h tile (phase B, reuses A/B)
  int lane = threadIdx.x & 63, wv = threadIdx.x >> 6;
  int wr = wv >> 1, wc = wv & 1;
  int rbase = blockIdx.x * 128;

  // ---- phase A ----
  f32x4 acc[2][4] = {};
  for (int k0 = 0; k0 < 768; k0 += 64) {
#pragma unroll
    for (int i = 0; i < 2; i++) {
      int base = i * 8192 + wv * 1024;
      int q = base + lane * 16;
      int row = q >> 7;
      int colb = (q & 127) ^ ((row & 7) << 4);
      GLOAD_LDS16(agg + (size_t)(rbase + row) * 768 + k0 + (colb >> 1), Alds + base);
      GLOAD_LDS16(Wcat + (size_t)row * 768 + k0 + (colb >> 1), Blds + base);
    }
    __syncthreads();
#pragma unroll
    for (int kk = 0; kk < 2; kk++) {
      bf16x8 af[2], bv[4];
#pragma unroll
      for (int m = 0; m < 2; m++) {
        int row = wr * 32 + m * 16 + (lane & 15);
        int b = ((row << 7) + kk * 64 + ((lane >> 4) << 4)) ^ ((row & 7) << 4);
        af[m] = *(const bf16x8*)(Alds + b);
      }
#pragma unroll
      for (int nf = 0; nf < 4; nf++) {
        int row = wc * 64 + nf * 16 + (lane & 15);
        int b = ((row << 7) + kk * 64 + ((lane >> 4) << 4)) ^ ((row & 7) << 4);
        bv[nf] = *(const bf16x8*)(Blds + b);
      }
#pragma unroll
      for (int m = 0; m < 2; m++)
#pragma unroll
        for (int nf = 0; nf < 4; nf++)
          acc[m][nf] = mfma16(af[m], bv[nf], acc[m][nf]);
    }
    __syncthreads();
  }
  // h-tile staging (overwrites Alds/Blds; all phase-A reads done)
#pragma unroll
  for (int i = 0; i < 4; i++) {
    int base = i * 8192 + wv * 1024;
    int q = base + lane * 16;
    int row = q >> 8;
    int colb = (q & 255) ^ ((row & 7) << 4);
    GLOAD_LDS16(hbfin + (size_t)(node0 + rbase + row) * HD + (colb >> 1), Hlds + base);
  }
  // epilogue: msgs -> Mlds (swizzled); overlaps h-tile load latency
#pragma unroll
  for (int m = 0; m < 2; m++) {
#pragma unroll
    for (int r = 0; r < 4; r++) {
      int rloc = wr * 32 + m * 16 + (lane >> 4) * 4 + r;
      int node = node0 + rbase + rloc;
      float dv = divf[node];
      const int* c6 = cnt6 + (size_t)node * 6;
      int c[6];
#pragma unroll
      for (int e = 0; e < 6; e++) c[e] = c6[e];
#pragma unroll
      for (int nf = 0; nf < 4; nf++) {
        int col = wc * 64 + nf * 16 + (lane & 15);
        float badd = 0.f;
#pragma unroll
        for (int e = 0; e < 6; e++) badd += (float)c[e] * b_msg[e * 128 + col];
        float v = (acc[m][nf][r] + badd) / dv + 1e-8f;
        int b = ((rloc << 8) + col * 2) ^ ((rloc & 7) << 4);
        *(ushort_t*)(Mlds + b) = f2bf(v);
      }
    }
  }
  __syncthreads();

  // ---- phase B: GRU ----
  int d = wv * 16 + (lane & 15);
  float bir = b_ih[d],       bhr = b_hh[d];
  float biz = b_ih[128 + d], bhz = b_hh[128 + d];
  float bin = b_ih[256 + d], bhn = b_hh[256 + d];
#pragma unroll
  for (int rd = 0; rd < 4; rd++) {
    f32x4 acb[2][6] = {};
#pragma unroll
    for (int ks = 0; ks < 4; ks++) {
      bf16x8 am[2], ah[2];
#pragma unroll
      for (int m = 0; m < 2; m++) {
        int row = rd * 32 + m * 16 + (lane & 15);
        int b = ((row << 8) + ks * 64 + ((lane >> 4) << 4)) ^ ((row & 7) << 4);
        am[m] = *(const bf16x8*)(Mlds + b);
        ah[m] = *(const bf16x8*)(Hlds + b);
      }
      bf16x8 bi[3], bh[3];
#pragma unroll
      for (int g = 0; g < 3; g++) {
        int nidx = g * 128 + d;
        int ko = ks * 32 + ((lane >> 4) << 3);
        bi[g] = *(const bf16x8*)(wihb + (size_t)nidx * HD + ko);
        bh[g] = *(const bf16x8*)(whhb + (size_t)nidx * HD + ko);
      }
#pragma unroll
      for (int m = 0; m < 2; m++)
#pragma unroll
        for (int g = 0; g < 3; g++) {
          acb[m][g]     = mfma16(am[m], bi[g], acb[m][g]);
          acb[m][3 + g] = mfma16(ah[m], bh[g], acb[m][3 + g]);
        }
    }
#pragma unroll
    for (int m = 0; m < 2; m++) {
#pragma unroll
      for (int r = 0; r < 4; r++) {
        int rloc = rd * 32 + m * 16 + (lane >> 4) * 4 + r;
        int row = node0 + rbase + rloc;
        if (row < NN) {
          float ir = acb[m][0][r], iz = acb[m][1][r], in = acb[m][2][r];
          float hr = acb[m][3][r], hz = acb[m][4][r], hn = acb[m][5][r];
          float rg = 1.f / (1.f + expf(-(ir + hr + bir + bhr)));
          float zg = 1.f / (1.f + expf(-(iz + hz + biz + bhz)));
          float ng = tanhf(in + bin + rg * (hn + bhn));
          int hb = ((rloc << 8) + d * 2) ^ ((rloc & 7) << 4);
          float hold = bf2f(*(const ushort_t*)(Hlds + hb));
          float o = (1.f - zg) * ng + zg * hold;
          size_t idx = (size_t)row * HD + d;
          hbfout[idx] = f2bf(o);
          if (last) hf[idx] = o;
        }
      }
    }
  }
}

// ---------- host ----------

extern "C" void kernel_launch(void* const* d_in, const int* in_sizes, int n_in,
                              void* d_out, int out_size, void* d_ws, size_t ws_size,
                              hipStream_t stream) {
  const float* node_states = (const float*)d_in[0];
  const int*   edges       = (const int*)d_in[1];
  const float* W_msg       = (const float*)d_in[2];
  const float* b_msg       = (const float*)d_in[3];
  const float* w_ih        = (const float*)d_in[4];
  const float* w_hh        = (const float*)d_in[5];
  const float* b_ih        = (const float*)d_in[6];
  const float* b_hh        = (const float*)d_in[7];
  float* out_h   = (float*)d_out;
  float* out_old = out_h + (size_t)NN * HD;

  char* p = (char*)d_ws;
  auto carve = [&](size_t bytes) { char* r = p; p += (bytes + 255) & ~(size_t)255; return r; };
  ushort_t* hbfA  = (ushort_t*)carve((size_t)NP * HD * 2);
  ushort_t* hbfB  = (ushort_t*)carve((size_t)NP * HD * 2);
  ushort_t* Wcat  = (ushort_t*)carve((size_t)128 * 768 * 2);
  ushort_t* wihb  = (ushort_t*)carve((size_t)384 * 128 * 2);
  ushort_t* whhb  = (ushort_t*)carve((size_t)384 * 128 * 2);
  int*   cnt6     = (int*)carve((size_t)L6P * 4);
  float* divf     = (float*)carve((size_t)NP * 4);
  int*   offs6    = (int*)carve((size_t)(L6P + 1) * 4);
  int*   entries  = (int*)carve((size_t)TOT * 4);
  int*   bsum     = (int*)carve(512 * 4);
  int*   rcnt     = (int*)carve((size_t)NREG * 4);
  int*   rbuf     = (int*)carve((size_t)NREG * RCAP * 4);   // 12.8MB, setup-only
  size_t used  = (size_t)(p - (char*)d_ws);
  size_t avail = ws_size > used ? ws_size - used : 0;
  size_t chunk_rows = avail / (768 * 2);
  if (chunk_rows > (size_t)CHROWS) chunk_rows = CHROWS;
  chunk_rows &= ~(size_t)127;
  if (chunk_rows < 128) chunk_rows = 128;
  ushort_t* agg = (ushort_t*)p;

  hipMemsetAsync(rcnt, 0, (size_t)NREG * 4, stream);
  hipMemsetAsync(hbfA + (size_t)NN * HD, 0, (size_t)(NP - NN) * HD * 2, stream);
  hipMemsetAsync(hbfB + (size_t)NN * HD, 0, (size_t)(NP - NN) * HD * 2, stream);

  k_init<<<(NN * HD + 255) / 256, 256, 0, stream>>>(node_states, out_h, out_old, hbfA);
  k_prep<<<(128 * 768 + 255) / 256, 256, 0, stream>>>(W_msg, w_ih, w_hh, Wcat, wihb, whhb);
  k_bin1<<<256, 256, 0, stream>>>(edges, rcnt, rbuf);
  k_bin2<<<NREG, 256, 0, stream>>>(rcnt, rbuf, cnt6);
  k_div<<<(NP + 255) / 256, 256, 0, stream>>>(cnt6, divf);
  int nb = (L6P + SCHUNK - 1) / SCHUNK;   // 294
  k_scan1<<<nb, 256, 0, stream>>>(cnt6, bsum);
  k_scan2<<<1, 512, 0, stream>>>(bsum, nb);
  k_scan3<<<nb, 256, 0, stream>>>(cnt6, bsum, offs6);
  k_bin3<<<NREG, 256, 0, stream>>>(rcnt, rbuf, offs6, entries);

  ushort_t* hA = hbfA;
  ushort_t* hB = hbfB;
  for (int L = 0; L < NLAYER; L++) {
    int last = (L == NLAYER - 1);
    for (size_t n0 = 0; n0 < (size_t)NP; n0 += chunk_rows) {
      int rows = (int)(((size_t)NP - n0) < chunk_rows ? ((size_t)NP - n0) : chunk_rows);
      k_agg<<<(rows + 15) / 16, 512, 0, stream>>>(hA, offs6, entries, agg, (int)n0, rows);
      k_fused<<<rows / 128, 512, 0, stream>>>(agg, Wcat, cnt6, divf, b_msg, hA,
                                              wihb, whhb, b_ih, b_hh,
                                              out_h, hB, (int)n0, last);
    }
    ushort_t* tmp = hA; hA = hB; hB = tmp;
  }
}

// Round 12
// 2656.106 us; speedup vs baseline: 1.4628x; 1.4628x over previous
//
#include <hip/hip_runtime.h>

#define NN     100000
#define NP     100096   // padded: = 391 * 256
#define HD     128
#define NE     400000
#define TOT    2400000  // 6 * NE
#define L6P    (NP * 6)
#define NLAYER 8
#define SCHUNK 2048
#define CHROWS 50176    // layer chunk (agg 77MB; WS ~148MB < 256MB L3)
#define NREG   391      // 256-node target regions
#define RCAP   8192     // region bucket capacity (avg 6138)
#define BSEG   9375     // edges per k_bin1 block (256 blocks)

typedef unsigned short ushort_t;
typedef unsigned int   uint_t;

typedef __bf16 bf16x8 __attribute__((ext_vector_type(8)));
typedef float  f32x4  __attribute__((ext_vector_type(4)));

__device__ __forceinline__ f32x4 mfma16(bf16x8 a, bf16x8 b, f32x4 c) {
  return __builtin_amdgcn_mfma_f32_16x16x32_bf16(a, b, c, 0, 0, 0);
}

__device__ __forceinline__ unsigned short f2bf(float f) {
  unsigned int u = __builtin_bit_cast(unsigned int, f);
  u = (u + 0x7FFFu + ((u >> 16) & 1u)) >> 16;
  return (unsigned short)u;
}
__device__ __forceinline__ float bflo(uint_t v) { return __builtin_bit_cast(float, v << 16); }
__device__ __forceinline__ float bfhi(uint_t v) { return __builtin_bit_cast(float, v & 0xFFFF0000u); }
__device__ __forceinline__ float bf2f(ushort_t v) { return __builtin_bit_cast(float, (uint_t)v << 16); }
__device__ __forceinline__ uint_t packbf(float x, float y) {
  return (uint_t)f2bf(x) | ((uint_t)f2bf(y) << 16);
}

#define GLOAD_LDS16(g, l) __builtin_amdgcn_global_load_lds( \
    (__attribute__((address_space(1))) void*)(g),           \
    (__attribute__((address_space(3))) void*)(l), 16, 0, 0)

// ---------- setup kernels (once per call) ----------

__global__ __launch_bounds__(256) void k_init(const float* __restrict__ ns,
    float* __restrict__ oh, float* __restrict__ oold, ushort_t* __restrict__ hbf) {
  int i = blockIdx.x * 256 + threadIdx.x;
  if (i < NN * HD) {
    float v = ns[i];
    oh[i] = v; oold[i] = v; hbf[i] = f2bf(v);
  }
}

__global__ __launch_bounds__(256) void k_prep(const float* __restrict__ Wm,
    const float* __restrict__ wih, const float* __restrict__ whh,
    ushort_t* __restrict__ Wcat, ushort_t* __restrict__ wihb, ushort_t* __restrict__ whhb) {
  int t = blockIdx.x * 256 + threadIdx.x;
  if (t < 128 * 768) {
    int n = t / 768, k = t % 768;
    int e = k >> 7, d = k & 127;
    Wcat[t] = f2bf(Wm[(e * 128 + d) * 128 + n]);   // [n][k], N-major
  }
  if (t < 384 * 128) {
    wihb[t] = f2bf(wih[t]);
    whhb[t] = f2bf(whh[t]);
  }
}

// Pass A: block-local counting sort by target region, contiguous writeout.
// One global atomicAdd per (block,region) -- no contention (r6 lesson).
__global__ __launch_bounds__(256) void k_bin1(const int* __restrict__ edges,
    int* __restrict__ rcnt, int* __restrict__ rbuf) {
  __shared__ int hist[392], lbase[392], cur[392], gb[392], scanb[256];
  __shared__ int lsort[BSEG];
  int t = threadIdx.x;
  int e0 = blockIdx.x * BSEG;
  int e1 = e0 + BSEG < TOT ? e0 + BSEG : TOT;
  int cnt = e1 - e0;
  for (int i = t; i < 392; i += 256) hist[i] = 0;
  __syncthreads();
  for (int i = e0 + t; i < e1; i += 256) {
    int e = i / NE, m = i - e * NE;
    int tgt = (e < 3) ? edges[(e * NE + m) * 2 + 1] : edges[((e - 3) * NE + m) * 2];
    atomicAdd(&hist[tgt >> 8], 1);
  }
  __syncthreads();
  int h0 = hist[2 * t], h1 = (2 * t + 1 < 392) ? hist[2 * t + 1] : 0;
  scanb[t] = h0 + h1;
  __syncthreads();
  for (int off = 1; off < 256; off <<= 1) {
    int x = (t >= off) ? scanb[t - off] : 0;
    __syncthreads();
    scanb[t] += x;
    __syncthreads();
  }
  int excl = scanb[t] - (h0 + h1);
  if (2 * t < 392)     lbase[2 * t] = excl;
  if (2 * t + 1 < 392) lbase[2 * t + 1] = excl + h0;
  __syncthreads();
  for (int r = t; r < NREG; r += 256) {
    int h = hist[r];
    gb[r] = h ? atomicAdd(&rcnt[r], h) : 0;
    cur[r] = lbase[r];
  }
  __syncthreads();
  for (int i = e0 + t; i < e1; i += 256) {
    int e = i / NE, m = i - e * NE;
    int src, tgt;
    if (e < 3) { int b = (e * NE + m) * 2;       src = edges[b];     tgt = edges[b + 1]; }
    else       { int b = ((e - 3) * NE + m) * 2; src = edges[b + 1]; tgt = edges[b]; }
    int lp = atomicAdd(&cur[tgt >> 8], 1);
    lsort[lp] = src | (e << 17) | ((tgt & 255) << 20);
  }
  __syncthreads();
  for (int i = t; i < cnt; i += 256) {
    int lo = 0, hi = NREG - 1;                 // find r: lbase[r] <= i
    while (lo < hi) { int mid = (lo + hi + 1) >> 1; if (lbase[mid] <= i) lo = mid; else hi = mid - 1; }
    rbuf[(size_t)lo * RCAP + gb[lo] + (i - lbase[lo])] = lsort[i];
  }
}

// Pass B: per-region LDS histogram -> dense cnt6
__global__ __launch_bounds__(256) void k_bin2(const int* __restrict__ rcnt,
    const int* __restrict__ rbuf, int* __restrict__ cnt6) {
  __shared__ int hist[1536];
  int R = blockIdx.x;
#pragma unroll
  for (int j = 0; j < 6; j++) hist[threadIdx.x + j * 256] = 0;
  __syncthreads();
  int n = rcnt[R];
  for (int i = threadIdx.x; i < n; i += 256) {
    int v = rbuf[(size_t)R * RCAP + i];
    atomicAdd(&hist[((v >> 20) & 255) * 6 + ((v >> 17) & 7)], 1);
  }
  __syncthreads();
#pragma unroll
  for (int j = 0; j < 6; j++) {
    int idx = threadIdx.x + j * 256;
    cnt6[(size_t)R * 1536 + idx] = hist[idx];
  }
}

// Pass C: per-region CSR fill; LDS cursors, entries window L2-resident
__global__ __launch_bounds__(256) void k_bin3(const int* __restrict__ rcnt,
    const int* __restrict__ rbuf, const int* __restrict__ offs6,
    int* __restrict__ entries) {
  __shared__ int curloc[1536];
  int R = blockIdx.x;
#pragma unroll
  for (int j = 0; j < 6; j++) {
    int idx = threadIdx.x + j * 256;
    curloc[idx] = offs6[(size_t)R * 1536 + idx];
  }
  __syncthreads();
  int n = rcnt[R];
  for (int i = threadIdx.x; i < n; i += 256) {
    int v = rbuf[(size_t)R * RCAP + i];
    int idx = ((v >> 20) & 255) * 6 + ((v >> 17) & 7);
    int pos = atomicAdd(&curloc[idx], 1);
    entries[pos] = v & 0x1FFFF;
  }
}

__global__ __launch_bounds__(256) void k_div(const int* __restrict__ cnt6,
    float* __restrict__ divf) {
  int i = blockIdx.x * 256 + threadIdx.x;
  if (i < NP) {
    int c = 0;
#pragma unroll
    for (int e = 0; e < 6; e++) c += cnt6[i * 6 + e];
    divf[i] = c ? (float)c : 1.0f;
  }
}

// exclusive scan over cnt6 (length L6P) -> offs6
__global__ __launch_bounds__(256) void k_scan1(const int* __restrict__ cnt, int* __restrict__ bsum) {
  int base = blockIdx.x * SCHUNK + threadIdx.x * 8;
  int s = 0;
#pragma unroll
  for (int j = 0; j < 8; j++) { int idx = base + j; s += (idx < L6P) ? cnt[idx] : 0; }
  for (int o = 32; o > 0; o >>= 1) s += __shfl_down(s, o);
  __shared__ int sm[4];
  if ((threadIdx.x & 63) == 0) sm[threadIdx.x >> 6] = s;
  __syncthreads();
  if (threadIdx.x == 0) bsum[blockIdx.x] = sm[0] + sm[1] + sm[2] + sm[3];
}

__global__ __launch_bounds__(512) void k_scan2(int* __restrict__ bsum, int nb) { // 1 block, nb<=512
  int t = threadIdx.x, lane = t & 63, wv = t >> 6;
  int orig = (t < nb) ? bsum[t] : 0;
  int v = orig;
  for (int o = 1; o < 64; o <<= 1) { int x = __shfl_up(v, o); if (lane >= o) v += x; }
  __shared__ int ws[8];
  if (lane == 63) ws[wv] = v;
  __syncthreads();
  int add = 0;
  for (int w = 0; w < wv; w++) add += ws[w];
  if (t < nb) bsum[t] = v - orig + add;   // exclusive
}

__global__ __launch_bounds__(256) void k_scan3(const int* __restrict__ cnt,
    const int* __restrict__ bsum, int* __restrict__ offs) {
  int base = blockIdx.x * SCHUNK + threadIdx.x * 8;
  int vals[8], pre[8];
  int s = 0;
#pragma unroll
  for (int j = 0; j < 8; j++) {
    int idx = base + j;
    vals[j] = (idx < L6P) ? cnt[idx] : 0;
    pre[j] = s; s += vals[j];
  }
  int lane = threadIdx.x & 63, wvi = threadIdx.x >> 6;
  int v = s;
  for (int o = 1; o < 64; o <<= 1) { int t = __shfl_up(v, o); if (lane >= o) v += t; }
  __shared__ int wsum[4];
  if (lane == 63) wsum[wvi] = v;
  __syncthreads();
  int wpre = 0;
  for (int w = 0; w < wvi; w++) wpre += wsum[w];
  int texcl = (v - s) + wpre + bsum[blockIdx.x];
#pragma unroll
  for (int j = 0; j < 8; j++) {
    int idx = base + j;
    if (idx < L6P) {
      offs[idx] = texcl + pre[j];
      if (idx == L6P - 1) offs[L6P] = texcl + pre[j] + vals[j];
    }
  }
}

// ---------- per-layer kernels ----------

// Wave-per-node aggregation (r9/r10 proven variant), two-group software
// pipeline: groups of 8 edges; issue group g+1's gathers BEFORE accumulating
// group g. Exactly-count load issue -> zero duplicate loads. Type boundaries
// flushed per-edge in uniform SALU.
#define FLUSH() do { switch (curE) {                        \
    case 0: a0x += cx; a0y += cy; break;                    \
    case 1: a1x += cx; a1y += cy; break;                    \
    case 2: a2x += cx; a2y += cy; break;                    \
    case 3: a3x += cx; a3y += cy; break;                    \
    case 4: a4x += cx; a4y += cy; break;                    \
    default: a5x += cx; a5y += cy; break; }                 \
    cx = 0.f; cy = 0.f; } while (0)

__global__ __launch_bounds__(512) void k_agg(const ushort_t* __restrict__ hbf,
    const int* __restrict__ offs6, const int* __restrict__ entries,
    ushort_t* __restrict__ agg, int node0, int rows) {
  int lane = threadIdx.x & 63, wv = threadIdx.x >> 6;
  int rloc = blockIdx.x * 8 + wv;
  if (rloc >= rows) return;
  int n = node0 + rloc;
  int voff = lane * 4;
  const char* hb = (const char*)hbf;
  float a0x = 0.f, a0y = 0.f, a1x = 0.f, a1y = 0.f, a2x = 0.f, a2y = 0.f;
  float a3x = 0.f, a3y = 0.f, a4x = 0.f, a4y = 0.f, a5x = 0.f, a5y = 0.f;
  float cx = 0.f, cy = 0.f;
  int curE = 0;

  int bj = offs6[n * 6 + (lane < 6 ? lane : 6)];   // lane j: S[min(j,6)]
  int S0    = __builtin_amdgcn_readlane(bj, 0);
  int total = __builtin_amdgcn_readlane(bj, 6) - S0;
  int nextB = __builtin_amdgcn_readlane(bj, 1) - S0;

  uint_t v[8];
  int j = 0, curC = 0, gcnt = 0;
  int ent = 0;
  if (total > 0) {
    ent = entries[S0 + (lane < total ? lane : total - 1)];
    int lim = total < 64 ? total : 64;
    gcnt = lim < 8 ? lim : 8;
#pragma unroll
    for (int u = 0; u < 8; u++)
      if (u < gcnt) {
        int si = __builtin_amdgcn_readlane(ent, u);
        v[u] = *(const uint_t*)(hb + ((size_t)(uint_t)si << 8) + voff);
      }
  }
  while (gcnt > 0) {
    int jn = j + gcnt;
    uint_t w[8];
    int ncnt = 0;
    if (jn < total) {
      if (jn >= curC + 64) {              // advance 64-entry preload chunk
        curC += 64;
        int rem = total - curC;
        ent = entries[S0 + curC + (lane < rem ? lane : rem - 1)];
      }
      int lim = total < curC + 64 ? total : curC + 64;
      ncnt = lim - jn; if (ncnt > 8) ncnt = 8;
#pragma unroll
      for (int u = 0; u < 8; u++)
        if (u < ncnt) {
          int si = __builtin_amdgcn_readlane(ent, jn + u - curC);
          w[u] = *(const uint_t*)(hb + ((size_t)(uint_t)si << 8) + voff);
        }
    }
#pragma unroll
    for (int u = 0; u < 8; u++) {
      if (u < gcnt) {
        while (curE < 5 && j + u == nextB) {
          FLUSH(); curE++;
          nextB = __builtin_amdgcn_readlane(bj, curE + 1) - S0;
        }
        cx += bflo(v[u]); cy += bfhi(v[u]);
      }
    }
    j = jn; gcnt = ncnt;
#pragma unroll
    for (int u = 0; u < 8; u++) v[u] = w[u];
  }
  while (curE < 5) { FLUSH(); curE++; }
  FLUSH();   // final segment (curE==5 -> a5)

  uint_t* outp = (uint_t*)(agg + (size_t)rloc * 768);
  outp[0 * 64 + lane] = packbf(a0x, a0y);
  outp[1 * 64 + lane] = packbf(a1x, a1y);
  outp[2 * 64 + lane] = packbf(a2x, a2y);
  outp[3 * 64 + lane] = packbf(a3x, a3y);
  outp[4 * 64 + lane] = packbf(a4x, a4y);
  outp[5 * 64 + lane] = packbf(a5x, a5y);
}

// Fused msgs-GEMM + GRU. Block = 128 nodes, 8 waves, 64KB LDS.
__global__ __launch_bounds__(512, 2) void k_fused(
    const ushort_t* __restrict__ agg, const ushort_t* __restrict__ Wcat,
    const int* __restrict__ cnt6, const float* __restrict__ divf,
    const float* __restrict__ b_msg, const ushort_t* __restrict__ hbfin,
    const ushort_t* __restrict__ wihb, const ushort_t* __restrict__ whhb,
    const float* __restrict__ b_ih, const float* __restrict__ b_hh,
    float* __restrict__ hf, ushort_t* __restrict__ hbfout,
    int node0, int last) {
  __shared__ char smem[65536];
  char* Alds = smem;             // 16KB (phase A), 128 rows x 128B
  char* Blds = smem + 16384;     // 16KB (phase A)
  char* Mlds = smem + 32768;     // 32KB msgs tile, 128 rows x 256B
  char* Hlds = smem;             // 32KB h tile (phase B, reuses A/B)
  int lane = threadIdx.x & 63, wv = threadIdx.x >> 6;
  int wr = wv >> 1, wc = wv & 1;
  int rbase = blockIdx.x * 128;

  // ---- phase A ----
  f32x4 acc[2][4] = {};
  for (int k0 = 0; k0 < 768; k0 += 64) {
#pragma unroll
    for (int i = 0; i < 2; i++) {
      int base = i * 8192 + wv * 1024;
      int q = base + lane * 16;
      int row = q >> 7;
      int colb = (q & 127) ^ ((row & 7) << 4);
      GLOAD_LDS16(agg + (size_t)(rbase + row) * 768 + k0 + (colb >> 1), Alds + base);
      GLOAD_LDS16(Wcat + (size_t)row * 768 + k0 + (colb >> 1), Blds + base);
    }
    __syncthreads();
#pragma unroll
    for (int kk = 0; kk < 2; kk++) {
      bf16x8 af[2], bv[4];
#pragma unroll
      for (int m = 0; m < 2; m++) {
        int row = wr * 32 + m * 16 + (lane & 15);
        int b = ((row << 7) + kk * 64 + ((lane >> 4) << 4)) ^ ((row & 7) << 4);
        af[m] = *(const bf16x8*)(Alds + b);
      }
#pragma unroll
      for (int nf = 0; nf < 4; nf++) {
        int row = wc * 64 + nf * 16 + (lane & 15);
        int b = ((row << 7) + kk * 64 + ((lane >> 4) << 4)) ^ ((row & 7) << 4);
        bv[nf] = *(const bf16x8*)(Blds + b);
      }
#pragma unroll
      for (int m = 0; m < 2; m++)
#pragma unroll
        for (int nf = 0; nf < 4; nf++)
          acc[m][nf] = mfma16(af[m], bv[nf], acc[m][nf]);
    }
    __syncthreads();
  }
  // h-tile staging (overwrites Alds/Blds; all phase-A reads done)
#pragma unroll
  for (int i = 0; i < 4; i++) {
    int base = i * 8192 + wv * 1024;
    int q = base + lane * 16;
    int row = q >> 8;
    int colb = (q & 255) ^ ((row & 7) << 4);
    GLOAD_LDS16(hbfin + (size_t)(node0 + rbase + row) * HD + (colb >> 1), Hlds + base);
  }
  // epilogue: msgs -> Mlds (swizzled); overlaps h-tile load latency
#pragma unroll
  for (int m = 0; m < 2; m++) {
#pragma unroll
    for (int r = 0; r < 4; r++) {
      int rloc = wr * 32 + m * 16 + (lane >> 4) * 4 + r;
      int node = node0 + rbase + rloc;
      float dv = divf[node];
      const int* c6 = cnt6 + (size_t)node * 6;
      int c[6];
#pragma unroll
      for (int e = 0; e < 6; e++) c[e] = c6[e];
#pragma unroll
      for (int nf = 0; nf < 4; nf++) {
        int col = wc * 64 + nf * 16 + (lane & 15);
        float badd = 0.f;
#pragma unroll
        for (int e = 0; e < 6; e++) badd += (float)c[e] * b_msg[e * 128 + col];
        float v = (acc[m][nf][r] + badd) / dv + 1e-8f;
        int b = ((rloc << 8) + col * 2) ^ ((rloc & 7) << 4);
        *(ushort_t*)(Mlds + b) = f2bf(v);
      }
    }
  }
  __syncthreads();

  // ---- phase B: GRU ----
  int d = wv * 16 + (lane & 15);
  float bir = b_ih[d],       bhr = b_hh[d];
  float biz = b_ih[128 + d], bhz = b_hh[128 + d];
  float bin = b_ih[256 + d], bhn = b_hh[256 + d];
#pragma unroll
  for (int rd = 0; rd < 4; rd++) {
    f32x4 acb[2][6] = {};
#pragma unroll
    for (int ks = 0; ks < 4; ks++) {
      bf16x8 am[2], ah[2];
#pragma unroll
      for (int m = 0; m < 2; m++) {
        int row = rd * 32 + m * 16 + (lane & 15);
        int b = ((row << 8) + ks * 64 + ((lane >> 4) << 4)) ^ ((row & 7) << 4);
        am[m] = *(const bf16x8*)(Mlds + b);
        ah[m] = *(const bf16x8*)(Hlds + b);
      }
      bf16x8 bi[3], bh[3];
#pragma unroll
      for (int g = 0; g < 3; g++) {
        int nidx = g * 128 + d;
        int ko = ks * 32 + ((lane >> 4) << 3);
        bi[g] = *(const bf16x8*)(wihb + (size_t)nidx * HD + ko);
        bh[g] = *(const bf16x8*)(whhb + (size_t)nidx * HD + ko);
      }
#pragma unroll
      for (int m = 0; m < 2; m++)
#pragma unroll
        for (int g = 0; g < 3; g++) {
          acb[m][g]     = mfma16(am[m], bi[g], acb[m][g]);
          acb[m][3 + g] = mfma16(ah[m], bh[g], acb[m][3 + g]);
        }
    }
#pragma unroll
    for (int m = 0; m < 2; m++) {
#pragma unroll
      for (int r = 0; r < 4; r++) {
        int rloc = rd * 32 + m * 16 + (lane >> 4) * 4 + r;
        int row = node0 + rbase + rloc;
        if (row < NN) {
          float ir = acb[m][0][r], iz = acb[m][1][r], in = acb[m][2][r];
          float hr = acb[m][3][r], hz = acb[m][4][r], hn = acb[m][5][r];
          float rg = 1.f / (1.f + expf(-(ir + hr + bir + bhr)));
          float zg = 1.f / (1.f + expf(-(iz + hz + biz + bhz)));
          float ng = tanhf(in + bin + rg * (hn + bhn));
          int hb = ((rloc << 8) + d * 2) ^ ((rloc & 7) << 4);
          float hold = bf2f(*(const ushort_t*)(Hlds + hb));
          float o = (1.f - zg) * ng + zg * hold;
          size_t idx = (size_t)row * HD + d;
          hbfout[idx] = f2bf(o);
          if (last) hf[idx] = o;
        }
      }
    }
  }
}

// ---------- host ----------

extern "C" void kernel_launch(void* const* d_in, const int* in_sizes, int n_in,
                              void* d_out, int out_size, void* d_ws, size_t ws_size,
                              hipStream_t stream) {
  const float* node_states = (const float*)d_in[0];
  const int*   edges       = (const int*)d_in[1];
  const float* W_msg       = (const float*)d_in[2];
  const float* b_msg       = (const float*)d_in[3];
  const float* w_ih        = (const float*)d_in[4];
  const float* w_hh        = (const float*)d_in[5];
  const float* b_ih        = (const float*)d_in[6];
  const float* b_hh        = (const float*)d_in[7];
  float* out_h   = (float*)d_out;
  float* out_old = out_h + (size_t)NN * HD;

  char* p = (char*)d_ws;
  auto carve = [&](size_t bytes) { char* r = p; p += (bytes + 255) & ~(size_t)255; return r; };
  ushort_t* hbfA  = (ushort_t*)carve((size_t)NP * HD * 2);
  ushort_t* hbfB  = (ushort_t*)carve((size_t)NP * HD * 2);
  ushort_t* Wcat  = (ushort_t*)carve((size_t)128 * 768 * 2);
  ushort_t* wihb  = (ushort_t*)carve((size_t)384 * 128 * 2);
  ushort_t* whhb  = (ushort_t*)carve((size_t)384 * 128 * 2);
  int*   cnt6     = (int*)carve((size_t)L6P * 4);
  float* divf     = (float*)carve((size_t)NP * 4);
  int*   offs6    = (int*)carve((size_t)(L6P + 1) * 4);
  int*   entries  = (int*)carve((size_t)TOT * 4);
  int*   bsum     = (int*)carve(512 * 4);
  int*   rcnt     = (int*)carve((size_t)NREG * 4);
  int*   rbuf     = (int*)carve((size_t)NREG * RCAP * 4);   // 12.8MB, setup-only
  size_t used  = (size_t)(p - (char*)d_ws);
  size_t avail = ws_size > used ? ws_size - used : 0;
  size_t chunk_rows = avail / (768 * 2);
  if (chunk_rows > (size_t)CHROWS) chunk_rows = CHROWS;
  chunk_rows &= ~(size_t)127;
  if (chunk_rows < 128) chunk_rows = 128;
  ushort_t* agg = (ushort_t*)p;

  hipMemsetAsync(rcnt, 0, (size_t)NREG * 4, stream);
  hipMemsetAsync(hbfA + (size_t)NN * HD, 0, (size_t)(NP - NN) * HD * 2, stream);
  hipMemsetAsync(hbfB + (size_t)NN * HD, 0, (size_t)(NP - NN) * HD * 2, stream);

  k_init<<<(NN * HD + 255) / 256, 256, 0, stream>>>(node_states, out_h, out_old, hbfA);
  k_prep<<<(128 * 768 + 255) / 256, 256, 0, stream>>>(W_msg, w_ih, w_hh, Wcat, wihb, whhb);
  k_bin1<<<256, 256, 0, stream>>>(edges, rcnt, rbuf);
  k_bin2<<<NREG, 256, 0, stream>>>(rcnt, rbuf, cnt6);
  k_div<<<(NP + 255) / 256, 256, 0, stream>>>(cnt6, divf);
  int nb = (L6P + SCHUNK - 1) / SCHUNK;   // 294
  k_scan1<<<nb, 256, 0, stream>>>(cnt6, bsum);
  k_scan2<<<1, 512, 0, stream>>>(bsum, nb);
  k_scan3<<<nb, 256, 0, stream>>>(cnt6, bsum, offs6);
  k_bin3<<<NREG, 256, 0, stream>>>(rcnt, rbuf, offs6, entries);

  ushort_t* hA = hbfA;
  ushort_t* hB = hbfB;
  for (int L = 0; L < NLAYER; L++) {
    int last = (L == NLAYER - 1);
    for (size_t n0 = 0; n0 < (size_t)NP; n0 += chunk_rows) {
      int rows = (int)(((size_t)NP - n0) < chunk_rows ? ((size_t)NP - n0) : chunk_rows);
      k_agg<<<(rows + 7) / 8, 512, 0, stream>>>(hA, offs6, entries, agg, (int)n0, rows);
      k_fused<<<rows / 128, 512, 0, stream>>>(agg, Wcat, cnt6, divf, b_msg, hA,
                                              wihb, whhb, b_ih, b_hh,
                                              out_h, hB, (int)n0, last);
    }
    ushort_t* tmp = hA; hA = hB; hB = tmp;
  }
}